// Round 6
// baseline (78.933 us; speedup 1.0000x reference)
//
#include <hip/hip_runtime.h>

// InnerProduct: x (B=4096, F=39, D=64) fp32 -> out (B, 741) fp32
// out[b, p(i,j)] = dot(x[b,i,:], x[b,j,:]) for i<j.
//
// R1: scattered 4B global stores -> 414 MB writes. Fix: LDS-staged coalesced
//     output copy.
// R2: forced unroll + launch_bounds VGPR cap -> spill -> 1 GB scratch traffic.
//     Fix: low-pressure loops, no wave clamp.
// R4: bf16 MFMA Gram (3 row-tiles of 16, 12 mfma/wave); kernel ~20 us,
//     harness poison/restore (~61 us) dominates the bench number.
// R5: fragments loaded straight from global (no input LDS round-trip) --
//     near-neutral: kernel was not staging-bound.
// R6: (a) pad rows masked out (no load issued) instead of clamped -> fetch
//     49 -> 41 MB; (b) no __syncthreads -- lds_out row is per-wave private,
//     each wave copies its own 741 floats out (185 float4 + 1 scalar), so
//     waves are independent end-to-end (no block tail).
//
// Fragment facts (guide-verified): A[m=lane&15][k=(lane>>4)*8+j], B symmetric
// (A==B content for Gram), C/D: col=lane&15, row=(lane>>4)*4+reg.

typedef __bf16 bf16x8 __attribute__((ext_vector_type(8)));
typedef float  f32x4  __attribute__((ext_vector_type(4)));

constexpr int NFIELD = 39;
constexpr int DIM    = 64;
constexpr int NPAIR  = 741;        // C(39,2)
constexpr int BPB    = 4;          // batches per block, one per wave

__global__ __launch_bounds__(256)
void ip_kernel(const float* __restrict__ x, float* __restrict__ out, int batches) {
    __shared__ __align__(16) float lds_out[BPB][NPAIR];   // 11856 B

    const int tid  = threadIdx.x;
    const int wv   = tid >> 6;
    const int lane = tid & 63;
    const int batch = blockIdx.x * BPB + wv;
    if (batch >= batches) return;          // waves are independent; no barrier

    const int m = lane & 15;       // fragment row within tile / out col
    const int q = lane >> 4;       // quad -> k sub-chunk + out row group
    const float* xb = x + (size_t)batch * (NFIELD * DIM);

    // ---- fragments straight from global: fr[t][s] = X[16t+m][32s+8q ..+8].
    //      Pad rows (t=2, m>=7): zero fragment, NO memory request issued.
    bf16x8 fr[3][2];
    #pragma unroll
    for (int t = 0; t < 3; ++t) {
        const int row = 16 * t + m;
        const bool ok = (row < NFIELD);
        #pragma unroll
        for (int s = 0; s < 2; ++s) {
            bf16x8 w;
            #pragma unroll
            for (int e = 0; e < 8; ++e) w[e] = (__bf16)0.0f;
            if (ok) {
                const float* p = xb + row * DIM + 32 * s + 8 * q;
                f32x4 u = *(const f32x4*)p;
                f32x4 v = *(const f32x4*)(p + 4);
                w[0] = (__bf16)u[0]; w[1] = (__bf16)u[1];
                w[2] = (__bf16)u[2]; w[3] = (__bf16)u[3];
                w[4] = (__bf16)v[0]; w[5] = (__bf16)v[1];
                w[6] = (__bf16)v[2]; w[7] = (__bf16)v[3];
            }
            fr[t][s] = w;
        }
    }

    // ---- 6 upper-tri tiles of the 3x3 block Gram, 12 MFMAs ----
    f32x4 a00 = {0.f,0.f,0.f,0.f}, a01 = a00, a02 = a00;
    f32x4 a11 = a00, a12 = a00, a22 = a00;
    #pragma unroll
    for (int s = 0; s < 2; ++s) {
        a00 = __builtin_amdgcn_mfma_f32_16x16x32_bf16(fr[0][s], fr[0][s], a00, 0, 0, 0);
        a01 = __builtin_amdgcn_mfma_f32_16x16x32_bf16(fr[0][s], fr[1][s], a01, 0, 0, 0);
        a02 = __builtin_amdgcn_mfma_f32_16x16x32_bf16(fr[0][s], fr[2][s], a02, 0, 0, 0);
        a11 = __builtin_amdgcn_mfma_f32_16x16x32_bf16(fr[1][s], fr[1][s], a11, 0, 0, 0);
        a12 = __builtin_amdgcn_mfma_f32_16x16x32_bf16(fr[1][s], fr[2][s], a12, 0, 0, 0);
        a22 = __builtin_amdgcn_mfma_f32_16x16x32_bf16(fr[2][s], fr[2][s], a22, 0, 0, 0);
    }

    // ---- scatter into this wave's private LDS row (cheap LDS scatter) ----
    auto scatter = [&](const f32x4& a, int ti, int tj) {
        #pragma unroll
        for (int r = 0; r < 4; ++r) {
            const int i = 16 * ti + 4 * q + r;   // C/D row
            const int j = 16 * tj + m;           // C/D col
            if (i < j && j < NFIELD) {
                const int p = 38 * i - (i * (i - 1)) / 2 + (j - i - 1);
                lds_out[wv][p] = a[r];
            }
        }
    };
    scatter(a00, 0, 0); scatter(a01, 0, 1); scatter(a02, 0, 2);
    scatter(a11, 1, 1); scatter(a12, 1, 2); scatter(a22, 2, 2);

    // ---- per-wave coalesced copy-out: 741 floats = 185 float4 + 1 ----
    // (lds_out[wv] is written and read by this wave only -> no barrier;
    //  compiler inserts the lgkmcnt wait on the LDS dependence.)
    float* dst = out + (size_t)batch * NPAIR;
    const float4* s4 = (const float4*)&lds_out[wv][0];
    float4* d4 = (float4*)dst;
    #pragma unroll
    for (int i = lane; i < NPAIR / 4; i += 64) d4[i] = s4[i];   // 185 float4
    if (lane == 0) dst[NPAIR - 1] = lds_out[wv][NPAIR - 1];     // element 740
}

extern "C" void kernel_launch(void* const* d_in, const int* in_sizes, int n_in,
                              void* d_out, int out_size, void* d_ws, size_t ws_size,
                              hipStream_t stream) {
    const float* x = (const float*)d_in[0];
    float* out     = (float*)d_out;
    const int batches = in_sizes[0] / (NFIELD * DIM);   // 4096
    const int blocks  = (batches + BPB - 1) / BPB;      // 1024
    ip_kernel<<<blocks, 256, 0, stream>>>(x, out, batches);
}